// Round 1
// baseline (329.398 us; speedup 1.0000x reference)
//
#include <hip/hip_runtime.h>
#include <hip/hip_bf16.h>

#define HW 65536
#define WIDTH 256

typedef __attribute__((ext_vector_type(8))) short short8;
typedef __attribute__((ext_vector_type(4))) float f32x4;

static __device__ __forceinline__ ushort f2bf(float f) {
    union { float f; unsigned u; } v; v.f = f;
    unsigned u = v.u;
    unsigned r = (u + 0x7fffu + ((u >> 16) & 1u)) >> 16;
    return (ushort)r;
}
static __device__ __forceinline__ float bf2f(ushort u) {
    union { unsigned u; float f; } v; v.u = ((unsigned)u) << 16; return v.f;
}
static __device__ __forceinline__ f32x4 mfma16(short8 a, short8 b, f32x4 c) {
    return __builtin_amdgcn_mfma_f32_16x16x32_bf16(a, b, c, 0, 0, 0);
}

// ---------------- prep: pack conv weights to bf16 [288][96]; fold W1/W2 ----------------
__global__ __launch_bounds__(256) void prep_kernel(
        const float* __restrict__ qc, const float* __restrict__ kvc,
        const float* __restrict__ qt, const float* __restrict__ kvt,
        const float* __restrict__ cw, const float* __restrict__ poc, const float* __restrict__ pot,
        ushort* __restrict__ Wc, ushort* __restrict__ Wt,
        float* __restrict__ W1, float* __restrict__ W2) {
    int bx = blockIdx.x, tid = threadIdx.x;
    if (bx == 0) {
        for (int idx = tid; idx < 288 * 96; idx += 256) {
            Wc[idx] = f2bf(idx < 96 * 96 ? qc[idx] : kvc[idx - 96 * 96]);
            Wt[idx] = f2bf(idx < 96 * 96 ? qt[idx] : kvt[idx - 96 * 96]);
        }
    } else {
        int idx = (bx - 1) * 256 + tid;          // 0..18431
        int sel = idx < 9216 ? 0 : 1;            // 0 -> W1 (c path), 1 -> W2 (t path)
        int i = sel ? idx - 9216 : idx;
        int o = i / 96, m = i % 96;
        const float* po = sel ? pot : poc;
        float acc = 0.f;
        for (int p = 0; p < 96; ++p)
            acc += cw[o * 192 + sel * 96 + p] * po[p * 96 + m];
        (sel ? W2 : W1)[i] = acc;
    }
}

// ---------------- conv1x1: Y[b,o,n] = sum_k W[o,k] * X[b,k,n], o in [0,288) ----------------
__global__ __launch_bounds__(256) void conv_kernel(const float* __restrict__ X,
                                                   const ushort* __restrict__ W,
                                                   ushort* __restrict__ Y) {
    __shared__ ushort xs[64][104];               // [pixel][k], padded stride
    int tid = threadIdx.x;
    int n0 = blockIdx.x * 64;
    int b = blockIdx.y;
    const float* Xb = X + (size_t)b * 96 * HW;
    for (int idx = tid; idx < 96 * 64; idx += 256) {
        int n = idx & 63, k = idx >> 6;
        xs[n][k] = f2bf(Xb[(size_t)k * HW + n0 + n]);
    }
    __syncthreads();
    int wave = tid >> 6, lane = tid & 63;
    int lr = lane & 15, lg = lane >> 4;
    short8 bfr[3];
    #pragma unroll
    for (int kk = 0; kk < 3; ++kk)
        bfr[kk] = *(const short8*)&xs[wave * 16 + lr][kk * 32 + lg * 8];
    f32x4 acc[18];
    #pragma unroll
    for (int mt = 0; mt < 18; ++mt) acc[mt] = (f32x4){0.f, 0.f, 0.f, 0.f};
    #pragma unroll
    for (int mt = 0; mt < 18; ++mt) {
        #pragma unroll
        for (int kk = 0; kk < 3; ++kk) {
            short8 a = *(const short8*)&W[(size_t)(mt * 16 + lr) * 96 + kk * 32 + lg * 8];
            acc[mt] = mfma16(a, bfr[kk], acc[mt]);
        }
    }
    ushort* Yb = Y + (size_t)b * 288 * HW;
    #pragma unroll
    for (int mt = 0; mt < 18; ++mt) {
        #pragma unroll
        for (int r = 0; r < 4; ++r) {
            int o = mt * 16 + lg * 4 + r;
            Yb[(size_t)o * HW + n0 + wave * 16 + lr] = f2bf(acc[mt][r]);
        }
    }
}

// ---------------- depthwise 3x3 SAME ----------------
__global__ __launch_bounds__(256) void dw_kernel(const ushort* __restrict__ Y,
                                                 const float* __restrict__ qdw,
                                                 const float* __restrict__ kvdw,
                                                 ushort* __restrict__ QKV) {
    __shared__ float tile[10][258];
    int tid = threadIdx.x;
    int ch = blockIdx.y % 288, b = blockIdx.y / 288;
    int r0 = blockIdx.x * 8;
    const float* w = (ch < 96) ? (qdw + ch * 9) : (kvdw + (ch - 96) * 9);
    float w00 = w[0], w01 = w[1], w02 = w[2], w10 = w[3], w11 = w[4],
          w12 = w[5], w20 = w[6], w21 = w[7], w22 = w[8];
    const ushort* src = Y + (size_t)(b * 288 + ch) * HW;
    for (int rr = 0; rr < 10; ++rr) {
        int row = r0 - 1 + rr;
        float v = (row >= 0 && row < 256) ? bf2f(src[row * 256 + tid]) : 0.f;
        tile[rr][tid + 1] = v;
    }
    if (tid < 10) { tile[tid][0] = 0.f; tile[tid][257] = 0.f; }
    __syncthreads();
    ushort* dst = QKV + (size_t)(b * 288 + ch) * HW;
    for (int r = 0; r < 8; ++r) {
        float acc = w00 * tile[r][tid] + w01 * tile[r][tid + 1] + w02 * tile[r][tid + 2]
                  + w10 * tile[r + 1][tid] + w11 * tile[r + 1][tid + 1] + w12 * tile[r + 1][tid + 2]
                  + w20 * tile[r + 2][tid] + w21 * tile[r + 2][tid + 1] + w22 * tile[r + 2][tid + 2];
        dst[(r0 + r) * 256 + tid] = f2bf(acc);
    }
}

// ---------------- Gram (q.k^T over n) + per-row sum-of-squares ----------------
__global__ __launch_bounds__(256) void gram_kernel(const ushort* __restrict__ QKVc,
                                                   const ushort* __restrict__ QKVt,
                                                   float* __restrict__ G,
                                                   float* __restrict__ SSQ) {
    __shared__ float Gp[4][32][32];
    int tid = threadIdx.x, wave = tid >> 6, lane = tid & 63;
    int lr = lane & 15, lg = lane >> 4;
    int code = blockIdx.y;                        // a*6 + b*3 + h
    int a = code / 6, b = (code % 6) / 3, h = code % 3;
    const ushort* qsrc = (a == 0) ? QKVc : QKVt;  // q of stream c (a=0) or t (a=1)
    const ushort* ksrc = (a == 0) ? QKVt : QKVc;  // k of opposite stream
    const ushort* qrow0 = qsrc + (size_t)(b * 288 + 32 * h + lr) * HW;
    const ushort* krow0 = ksrc + (size_t)(b * 288 + 96 + 32 * h + lr) * HW;
    f32x4 acc[2][2];
    #pragma unroll
    for (int i = 0; i < 2; ++i)
        #pragma unroll
        for (int j = 0; j < 2; ++j) acc[i][j] = (f32x4){0.f, 0.f, 0.f, 0.f};
    float sq[2] = {0.f, 0.f}, sk[2] = {0.f, 0.f};
    for (int s = wave; s < 16; s += 4) {
        int n = blockIdx.x * 512 + s * 32 + lg * 8;
        short8 aq[2], bk[2];
        aq[0] = *(const short8*)(qrow0 + n);
        aq[1] = *(const short8*)(qrow0 + (size_t)16 * HW + n);
        bk[0] = *(const short8*)(krow0 + n);
        bk[1] = *(const short8*)(krow0 + (size_t)16 * HW + n);
        #pragma unroll
        for (int i = 0; i < 2; ++i) {
            #pragma unroll
            for (int e = 0; e < 8; ++e) {
                float vq = bf2f((ushort)aq[i][e]); sq[i] += vq * vq;
                float vk = bf2f((ushort)bk[i][e]); sk[i] += vk * vk;
            }
        }
        acc[0][0] = mfma16(aq[0], bk[0], acc[0][0]);
        acc[0][1] = mfma16(aq[0], bk[1], acc[0][1]);
        acc[1][0] = mfma16(aq[1], bk[0], acc[1][0]);
        acc[1][1] = mfma16(aq[1], bk[1], acc[1][1]);
    }
    #pragma unroll
    for (int i = 0; i < 2; ++i)
        #pragma unroll
        for (int j = 0; j < 2; ++j)
            #pragma unroll
            for (int r = 0; r < 4; ++r)
                Gp[wave][i * 16 + lg * 4 + r][j * 16 + lr] = acc[i][j][r];
    __syncthreads();
    float* Gout = G + (size_t)code * 1024;
    for (int idx = tid; idx < 1024; idx += 256) {
        float ssum = 0.f;
        #pragma unroll
        for (int wv = 0; wv < 4; ++wv) ssum += (&Gp[wv][0][0])[idx];
        atomicAdd(&Gout[idx], ssum);
    }
    #pragma unroll
    for (int i = 0; i < 2; ++i) {
        float v = sq[i];
        v += __shfl_xor(v, 16); v += __shfl_xor(v, 32);
        if (lg == 0) atomicAdd(&SSQ[((a * 2 + b) * 2 + 0) * 96 + 32 * h + i * 16 + lr], v);
        float u = sk[i];
        u += __shfl_xor(u, 16); u += __shfl_xor(u, 32);
        if (lg == 0) atomicAdd(&SSQ[((a * 2 + b) * 2 + 1) * 96 + 32 * h + i * 16 + lr], u);
    }
}

// ---------------- softmax + fold attn into M matrices ----------------
__global__ __launch_bounds__(256) void attn_kernel(const float* __restrict__ G,
                                                   const float* __restrict__ SSQ,
                                                   const float* __restrict__ temperature,
                                                   const float* __restrict__ W1,
                                                   const float* __restrict__ W2,
                                                   ushort* __restrict__ Mcat) {
    __shared__ float nq[32], nk[32], A[32][32];
    int tid = threadIdx.x;
    int code = blockIdx.x;
    int a = code / 6, b = (code % 6) / 3, h = code % 3;
    if (tid < 32)
        nq[tid] = fmaxf(sqrtf(fmaxf(SSQ[((a * 2 + b) * 2 + 0) * 96 + 32 * h + tid], 0.f)), 1e-12f);
    else if (tid < 64)
        nk[tid - 32] = fmaxf(sqrtf(fmaxf(SSQ[((a * 2 + b) * 2 + 1) * 96 + 32 * h + (tid - 32)], 0.f)), 1e-12f);
    __syncthreads();
    if (tid < 32) {
        const float* g = G + (size_t)code * 1024 + tid * 32;
        float t = temperature[h];
        float lg[32];
        float inq = t / nq[tid];
        float mx = -1e30f;
        #pragma unroll
        for (int j = 0; j < 32; ++j) { lg[j] = g[j] * inq / nk[j]; mx = fmaxf(mx, lg[j]); }
        float ssum = 0.f;
        #pragma unroll
        for (int j = 0; j < 32; ++j) { lg[j] = expf(lg[j] - mx); ssum += lg[j]; }
        float inv = 1.f / ssum;
        #pragma unroll
        for (int j = 0; j < 32; ++j) A[tid][j] = lg[j] * inv;
    }
    __syncthreads();
    const float* Wm = (a == 0) ? W1 : W2;
    for (int idx = tid; idx < 96 * 32; idx += 256) {
        int o = idx >> 5, d = idx & 31;
        float acc = 0.f;
        #pragma unroll
        for (int i = 0; i < 32; ++i)
            acc += Wm[o * 96 + 32 * h + i] * A[i][d];
        Mcat[(size_t)(b * 96 + o) * 192 + a * 96 + 32 * h + d] = f2bf(acc);
    }
}

// ---------------- final: out = [M1 M2] . [v_t ; v_c] + bias ----------------
__global__ __launch_bounds__(256) void final_kernel(const ushort* __restrict__ QKVc,
                                                    const ushort* __restrict__ QKVt,
                                                    const ushort* __restrict__ Mcat,
                                                    const float* __restrict__ bias,
                                                    float* __restrict__ out) {
    __shared__ ushort vs[64][200];
    int tid = threadIdx.x;
    int n0 = blockIdx.x * 64, b = blockIdx.y;
    for (int idx = tid; idx < 64 * 192; idx += 256) {
        int n = idx & 63, d = idx >> 6;
        const ushort* src = (d < 96) ? (QKVt + (size_t)(b * 288 + 192 + d) * HW)
                                     : (QKVc + (size_t)(b * 288 + 192 + (d - 96)) * HW);
        vs[n][d] = src[n0 + n];
    }
    __syncthreads();
    int wave = tid >> 6, lane = tid & 63, lr = lane & 15, lg = lane >> 4;
    short8 bfr[6];
    #pragma unroll
    for (int kk = 0; kk < 6; ++kk)
        bfr[kk] = *(const short8*)&vs[wave * 16 + lr][kk * 32 + lg * 8];
    f32x4 acc[6];
    #pragma unroll
    for (int mt = 0; mt < 6; ++mt) {
        acc[mt] = (f32x4){0.f, 0.f, 0.f, 0.f};
        #pragma unroll
        for (int kk = 0; kk < 6; ++kk) {
            short8 aM = *(const short8*)&Mcat[(size_t)(b * 96 + mt * 16 + lr) * 192 + kk * 32 + lg * 8];
            acc[mt] = mfma16(aM, bfr[kk], acc[mt]);
        }
    }
    float* ob = out + (size_t)b * 96 * HW;
    #pragma unroll
    for (int mt = 0; mt < 6; ++mt) {
        #pragma unroll
        for (int r = 0; r < 4; ++r) {
            int o = mt * 16 + lg * 4 + r;
            ob[(size_t)o * HW + n0 + wave * 16 + lr] = acc[mt][r] + bias[o];
        }
    }
}

extern "C" void kernel_launch(void* const* d_in, const int* in_sizes, int n_in,
                              void* d_out, int out_size, void* d_ws, size_t ws_size,
                              hipStream_t stream) {
    const float* low    = (const float*)d_in[0];
    const float* high   = (const float*)d_in[1];
    const float* temp   = (const float*)d_in[2];
    const float* qc_w   = (const float*)d_in[3];
    const float* qdw_c  = (const float*)d_in[4];
    const float* kvc_w  = (const float*)d_in[5];
    const float* kvdw_c = (const float*)d_in[6];
    const float* qt_w   = (const float*)d_in[7];
    const float* qdw_t  = (const float*)d_in[8];
    const float* kvt_w  = (const float*)d_in[9];
    const float* kvdw_t = (const float*)d_in[10];
    const float* po_c   = (const float*)d_in[11];
    const float* po_t   = (const float*)d_in[12];
    const float* cw     = (const float*)d_in[13];
    const float* cb     = (const float*)d_in[14];
    float* out = (float*)d_out;

    char* ws = (char*)d_ws;
    const size_t SY = (size_t)2 * 288 * HW * 2;   // 75,497,472 B per big tensor
    ushort* Y    = (ushort*)(ws);
    ushort* QKVc = (ushort*)(ws + SY);
    ushort* QKVt = (ushort*)(ws + 2 * SY);
    char* p = ws + 3 * SY;
    ushort* Wc = (ushort*)p; p += 288 * 96 * 2;
    ushort* Wt = (ushort*)p; p += 288 * 96 * 2;
    float* W1  = (float*)p;  p += 96 * 96 * 4;
    float* W2  = (float*)p;  p += 96 * 96 * 4;
    float* G   = (float*)p;  p += 12 * 1024 * 4;
    float* SSQ = (float*)p;  p += 8 * 96 * 4;
    ushort* Mcat = (ushort*)p; p += 2 * 96 * 192 * 2;
    if ((size_t)(p - ws) > ws_size) return;       // workspace too small — bail

    hipMemsetAsync(G, 0, 12 * 1024 * 4 + 8 * 96 * 4, stream);
    prep_kernel<<<73, 256, 0, stream>>>(qc_w, kvc_w, qt_w, kvt_w, cw, po_c, po_t, Wc, Wt, W1, W2);
    // stream c from high
    conv_kernel<<<dim3(1024, 2), 256, 0, stream>>>(high, Wc, Y);
    dw_kernel<<<dim3(32, 576), 256, 0, stream>>>(Y, qdw_c, kvdw_c, QKVc);
    // stream t from low
    conv_kernel<<<dim3(1024, 2), 256, 0, stream>>>(low, Wt, Y);
    dw_kernel<<<dim3(32, 576), 256, 0, stream>>>(Y, qdw_t, kvdw_t, QKVt);
    gram_kernel<<<dim3(128, 12), 256, 0, stream>>>(QKVc, QKVt, G, SSQ);
    attn_kernel<<<12, 256, 0, stream>>>(G, SSQ, temp, W1, W2, Mcat);
    final_kernel<<<dim3(1024, 2), 256, 0, stream>>>(QKVc, QKVt, Mcat, cb, out);
}

// Round 2
// 250.397 us; speedup vs baseline: 1.3155x; 1.3155x over previous
//
#include <hip/hip_runtime.h>
#include <hip/hip_bf16.h>

#define HW 65536

typedef __attribute__((ext_vector_type(8))) short short8;
typedef __attribute__((ext_vector_type(4))) float f32x4;

static __device__ __forceinline__ ushort f2bf(float f) {
    union { float f; unsigned u; } v; v.f = f;
    unsigned u = v.u;
    unsigned r = (u + 0x7fffu + ((u >> 16) & 1u)) >> 16;
    return (ushort)r;
}
static __device__ __forceinline__ float bf2f(ushort u) {
    union { unsigned u; float f; } v; v.u = ((unsigned)u) << 16; return v.f;
}
// pack 2 floats -> 2 bf16 in one u32 (low = a). Emits v_cvt_pk_bf16_f32.
static __device__ __forceinline__ unsigned pk2(float a, float b) {
    __hip_bfloat162 h = __float22bfloat162_rn(make_float2(a, b));
    union { __hip_bfloat162 h; unsigned u; } c; c.h = h; return c.u;
}
static __device__ __forceinline__ f32x4 mfma16(short8 a, short8 b, f32x4 c) {
    return __builtin_amdgcn_mfma_f32_16x16x32_bf16(a, b, c, 0, 0, 0);
}
union U8 { short8 s; unsigned u[4]; };

// ---------------- prep: pack conv weights to bf16 [288][96]; fold W1/W2 ----------------
__global__ __launch_bounds__(256) void prep_kernel(
        const float* __restrict__ qc, const float* __restrict__ kvc,
        const float* __restrict__ qt, const float* __restrict__ kvt,
        const float* __restrict__ cw, const float* __restrict__ poc, const float* __restrict__ pot,
        ushort* __restrict__ Wc, ushort* __restrict__ Wt,
        float* __restrict__ W1, float* __restrict__ W2) {
    int bx = blockIdx.x, tid = threadIdx.x;
    if (bx == 0) {
        for (int idx = tid; idx < 288 * 96; idx += 256) {
            Wc[idx] = f2bf(idx < 96 * 96 ? qc[idx] : kvc[idx - 96 * 96]);
            Wt[idx] = f2bf(idx < 96 * 96 ? qt[idx] : kvt[idx - 96 * 96]);
        }
    } else {
        int idx = (bx - 1) * 256 + tid;          // 0..18431
        int sel = idx < 9216 ? 0 : 1;            // 0 -> W1 (c path), 1 -> W2 (t path)
        int i = sel ? idx - 9216 : idx;
        int o = i / 96, m = i % 96;
        const float* po = sel ? pot : poc;
        float acc = 0.f;
        for (int p = 0; p < 96; ++p)
            acc += cw[o * 192 + sel * 96 + p] * po[p * 96 + m];
        (sel ? W2 : W1)[i] = acc;
    }
}

// ---------------- conv1x1: Y[b,o,n] = sum_k W[o,k]*X[b,k,n], o in [0,288), n-tile 128 ----------------
__global__ __launch_bounds__(256) void conv_kernel(const float* __restrict__ X,
                                                   const ushort* __restrict__ W,
                                                   ushort* __restrict__ Y) {
    __shared__ ushort xs[96 * 130];          // [k][n], stride 130 ushorts (odd word stride)
    __shared__ ushort ybuf[2][128 * 18];     // staging transposed [n][o], stride 18
    int tid = threadIdx.x;
    int n0 = blockIdx.x * 128;
    int b = blockIdx.y;
    const float* Xb = X + (size_t)b * 96 * HW + n0;
    // stage X (fp32 -> bf16): 96 k-rows x 32 n-quads
    #pragma unroll
    for (int i = 0; i < 12; ++i) {
        int idx = tid + i * 256;
        int nq = idx & 31, k = idx >> 5;
        float4 v = *(const float4*)(Xb + (size_t)k * HW + 4 * nq);
        unsigned* dst = (unsigned*)&xs[k * 130 + 4 * nq];
        dst[0] = pk2(v.x, v.y);
        dst[1] = pk2(v.z, v.w);
    }
    __syncthreads();
    int wave = tid >> 6, lane = tid & 63, lr = lane & 15, lg = lane >> 4;
    // build B-frags (X): 2 n-subtiles x 3 k-steps via conflict-free scalar u16 reads
    short8 bf[2][3];
    #pragma unroll
    for (int nt = 0; nt < 2; ++nt) {
        int n = wave * 32 + nt * 16 + lr;
        #pragma unroll
        for (int kk = 0; kk < 3; ++kk) {
            int kb = kk * 32 + lg * 8;
            U8 t;
            #pragma unroll
            for (int j = 0; j < 4; ++j) {
                unsigned e0 = xs[(kb + 2 * j) * 130 + n];
                unsigned e1 = xs[(kb + 2 * j + 1) * 130 + n];
                t.u[j] = e0 | (e1 << 16);
            }
            bf[nt][kk] = t.s;
        }
    }
    ushort* Yb = Y + (size_t)b * 288 * HW + n0;
    for (int mt = 0; mt < 18; ++mt) {
        f32x4 acc0 = {0.f, 0.f, 0.f, 0.f}, acc1 = {0.f, 0.f, 0.f, 0.f};
        #pragma unroll
        for (int kk = 0; kk < 3; ++kk) {
            short8 a = *(const short8*)&W[(size_t)(mt * 16 + lr) * 96 + kk * 32 + lg * 8];
            acc0 = mfma16(a, bf[0][kk], acc0);
            acc1 = mfma16(a, bf[1][kk], acc1);
        }
        // stage transposed [n][o]: pack o-pairs (rows lg*4+r are consecutive o)
        ushort* yb = ybuf[mt & 1];
        {
            unsigned* d0 = (unsigned*)&yb[(wave * 32 + lr) * 18 + lg * 4];
            d0[0] = pk2(acc0[0], acc0[1]);
            d0[1] = pk2(acc0[2], acc0[3]);
            unsigned* d1 = (unsigned*)&yb[(wave * 32 + 16 + lr) * 18 + lg * 4];
            d1[0] = pk2(acc1[0], acc1[1]);
            d1[1] = pk2(acc1[2], acc1[3]);
        }
        __syncthreads();
        // cooperative vector store: 16 o-rows x 128 n
        {
            int o = tid >> 4, g = tid & 15;
            U8 t;
            #pragma unroll
            for (int j = 0; j < 4; ++j) {
                unsigned e0 = yb[(8 * g + 2 * j) * 18 + o];
                unsigned e1 = yb[(8 * g + 2 * j + 1) * 18 + o];
                t.u[j] = e0 | (e1 << 16);
            }
            *(short8*)&Yb[(size_t)(mt * 16 + o) * HW + 8 * g] = t.s;
        }
    }
}

// ---------------- depthwise 3x3 SAME: 32-row tile, shfl halo ----------------
__global__ __launch_bounds__(256) void dw_kernel(const ushort* __restrict__ Y,
                                                 const float* __restrict__ qdw,
                                                 const float* __restrict__ kvdw,
                                                 ushort* __restrict__ QKV) {
    __shared__ ushort tile[34 * 256];
    int tid = threadIdx.x;
    int ch = blockIdx.y % 288, b = blockIdx.y / 288;
    int r0 = blockIdx.x * 32;
    const float* w = (ch < 96) ? (qdw + ch * 9) : (kvdw + (ch - 96) * 9);
    float w00 = w[0], w01 = w[1], w02 = w[2], w10 = w[3], w11 = w[4],
          w12 = w[5], w20 = w[6], w21 = w[7], w22 = w[8];
    const ushort* src = Y + (size_t)(b * 288 + ch) * HW;
    #pragma unroll
    for (int i = 0; i < 5; ++i) {
        int idx = tid + i * 256;
        if (idx < 34 * 32) {
            int row = idx >> 5, g = idx & 31;
            int gr = r0 - 1 + row;
            short8 v;
            if (gr >= 0 && gr < 256) v = *(const short8*)(src + gr * 256 + 8 * g);
            else v = (short8){0, 0, 0, 0, 0, 0, 0, 0};
            *(short8*)&tile[row * 256 + 8 * g] = v;
        }
    }
    __syncthreads();
    int wave = tid >> 6, lane = tid & 63;
    float rows[3][6];
    #define LOADROW(LROW, D)                                                 \
    {                                                                        \
        ushort4 t4 = *(const ushort4*)&tile[(LROW) * 256 + 4 * lane];        \
        float c0 = bf2f(t4.x), c1 = bf2f(t4.y), c2 = bf2f(t4.z), c3 = bf2f(t4.w); \
        float lft = __shfl(c3, lane - 1);                                    \
        float rgt = __shfl(c0, lane + 1);                                    \
        if (lane == 0) lft = 0.f;                                            \
        if (lane == 63) rgt = 0.f;                                           \
        D[0] = lft; D[1] = c0; D[2] = c1; D[3] = c2; D[4] = c3; D[5] = rgt;  \
    }
    LOADROW(wave * 8 + 0, rows[0]);
    LOADROW(wave * 8 + 1, rows[1]);
    ushort* dst = QKV + (size_t)(b * 288 + ch) * HW;
    #pragma unroll
    for (int orow = 0; orow < 8; ++orow) {
        LOADROW(wave * 8 + orow + 2, rows[(orow + 2) % 3]);
        float* ra = rows[orow % 3];
        float* rb = rows[(orow + 1) % 3];
        float* rc = rows[(orow + 2) % 3];
        float acc[4];
        #pragma unroll
        for (int j = 0; j < 4; ++j)
            acc[j] = w00 * ra[j] + w01 * ra[j + 1] + w02 * ra[j + 2]
                   + w10 * rb[j] + w11 * rb[j + 1] + w12 * rb[j + 2]
                   + w20 * rc[j] + w21 * rc[j + 1] + w22 * rc[j + 2];
        uint2 pv;
        pv.x = pk2(acc[0], acc[1]);
        pv.y = pk2(acc[2], acc[3]);
        *(uint2*)&dst[(r0 + wave * 8 + orow) * 256 + 4 * lane] = pv;
    }
    #undef LOADROW
}

// ---------------- Gram (q.k^T over n) + norms via diagonal MFMAs ----------------
__global__ __launch_bounds__(256) void gram_kernel(const ushort* __restrict__ QKVc,
                                                   const ushort* __restrict__ QKVt,
                                                   float* __restrict__ G,
                                                   float* __restrict__ SSQ) {
    __shared__ float Gp[4][32][32];
    int tid = threadIdx.x, wave = tid >> 6, lane = tid & 63;
    int lr = lane & 15, lg = lane >> 4;
    int code = blockIdx.y;                        // a*6 + b*3 + h
    int a = code / 6, b = (code % 6) / 3, h = code % 3;
    const ushort* qsrc = (a == 0) ? QKVc : QKVt;
    const ushort* ksrc = (a == 0) ? QKVt : QKVc;
    const ushort* qrow0 = qsrc + (size_t)(b * 288 + 32 * h + lr) * HW;
    const ushort* krow0 = ksrc + (size_t)(b * 288 + 96 + 32 * h + lr) * HW;
    f32x4 acc[2][2], aqq[2], akk[2];
    #pragma unroll
    for (int i = 0; i < 2; ++i) {
        aqq[i] = (f32x4){0.f, 0.f, 0.f, 0.f};
        akk[i] = (f32x4){0.f, 0.f, 0.f, 0.f};
        #pragma unroll
        for (int j = 0; j < 2; ++j) acc[i][j] = (f32x4){0.f, 0.f, 0.f, 0.f};
    }
    for (int s = wave; s < 32; s += 4) {
        int n = blockIdx.x * 1024 + s * 32 + lg * 8;
        short8 aq[2], bk[2];
        aq[0] = *(const short8*)(qrow0 + n);
        aq[1] = *(const short8*)(qrow0 + (size_t)16 * HW + n);
        bk[0] = *(const short8*)(krow0 + n);
        bk[1] = *(const short8*)(krow0 + (size_t)16 * HW + n);
        acc[0][0] = mfma16(aq[0], bk[0], acc[0][0]);
        acc[0][1] = mfma16(aq[0], bk[1], acc[0][1]);
        acc[1][0] = mfma16(aq[1], bk[0], acc[1][0]);
        acc[1][1] = mfma16(aq[1], bk[1], acc[1][1]);
        aqq[0] = mfma16(aq[0], aq[0], aqq[0]);
        aqq[1] = mfma16(aq[1], aq[1], aqq[1]);
        akk[0] = mfma16(bk[0], bk[0], akk[0]);
        akk[1] = mfma16(bk[1], bk[1], akk[1]);
    }
    #pragma unroll
    for (int i = 0; i < 2; ++i)
        #pragma unroll
        for (int j = 0; j < 2; ++j)
            #pragma unroll
            for (int r = 0; r < 4; ++r)
                Gp[wave][i * 16 + lg * 4 + r][j * 16 + lr] = acc[i][j][r];
    __syncthreads();
    float* Gout = G + (size_t)code * 1024;
    for (int idx = tid; idx < 1024; idx += 256) {
        float ssum = 0.f;
        #pragma unroll
        for (int wv = 0; wv < 4; ++wv) ssum += (&Gp[wv][0][0])[idx];
        atomicAdd(&Gout[idx], ssum);
    }
    int qbase = ((a * 2 + b) * 2 + 0) * 96 + 32 * h;
    int kbase = ((a * 2 + b) * 2 + 1) * 96 + 32 * h;
    #pragma unroll
    for (int i = 0; i < 2; ++i)
        #pragma unroll
        for (int r = 0; r < 4; ++r)
            if (lr == lg * 4 + r) {
                atomicAdd(&SSQ[qbase + i * 16 + lr], aqq[i][r]);
                atomicAdd(&SSQ[kbase + i * 16 + lr], akk[i][r]);
            }
}

// ---------------- softmax + fold attn into M matrices ----------------
__global__ __launch_bounds__(256) void attn_kernel(const float* __restrict__ G,
                                                   const float* __restrict__ SSQ,
                                                   const float* __restrict__ temperature,
                                                   const float* __restrict__ W1,
                                                   const float* __restrict__ W2,
                                                   ushort* __restrict__ Mcat) {
    __shared__ float nq[32], nk[32], A[32][32];
    int tid = threadIdx.x;
    int code = blockIdx.x;
    int a = code / 6, b = (code % 6) / 3, h = code % 3;
    if (tid < 32)
        nq[tid] = fmaxf(sqrtf(fmaxf(SSQ[((a * 2 + b) * 2 + 0) * 96 + 32 * h + tid], 0.f)), 1e-12f);
    else if (tid < 64)
        nk[tid - 32] = fmaxf(sqrtf(fmaxf(SSQ[((a * 2 + b) * 2 + 1) * 96 + 32 * h + (tid - 32)], 0.f)), 1e-12f);
    __syncthreads();
    if (tid < 32) {
        const float* g = G + (size_t)code * 1024 + tid * 32;
        float t = temperature[h];
        float lgv[32];
        float inq = t / nq[tid];
        float mx = -1e30f;
        #pragma unroll
        for (int j = 0; j < 32; ++j) { lgv[j] = g[j] * inq / nk[j]; mx = fmaxf(mx, lgv[j]); }
        float ssum = 0.f;
        #pragma unroll
        for (int j = 0; j < 32; ++j) { lgv[j] = expf(lgv[j] - mx); ssum += lgv[j]; }
        float inv = 1.f / ssum;
        #pragma unroll
        for (int j = 0; j < 32; ++j) A[tid][j] = lgv[j] * inv;
    }
    __syncthreads();
    const float* Wm = (a == 0) ? W1 : W2;
    for (int idx = tid; idx < 96 * 32; idx += 256) {
        int o = idx >> 5, d = idx & 31;
        float acc = 0.f;
        #pragma unroll
        for (int i = 0; i < 32; ++i)
            acc += Wm[o * 96 + 32 * h + i] * A[i][d];
        Mcat[(size_t)(b * 96 + o) * 192 + a * 96 + 32 * h + d] = f2bf(acc);
    }
}

// ---------------- final: out = [M1 M2].[v_t ; v_c] + bias, n-tile 128 ----------------
__global__ __launch_bounds__(256) void final_kernel(const ushort* __restrict__ QKVc,
                                                    const ushort* __restrict__ QKVt,
                                                    const ushort* __restrict__ Mcat,
                                                    const float* __restrict__ bias,
                                                    float* __restrict__ out) {
    __shared__ ushort vs[192 * 130];         // [d][n], stride 130
    __shared__ float obuf[2][16 * 132];      // fp32 staging, stride 132
    int tid = threadIdx.x;
    int n0 = blockIdx.x * 128, b = blockIdx.y;
    #pragma unroll
    for (int i = 0; i < 12; ++i) {
        int idx = tid + i * 256;
        int g = idx & 15, d = idx >> 4;
        const ushort* sp = (d < 96) ? (QKVt + (size_t)(b * 288 + 192 + d) * HW)
                                    : (QKVc + (size_t)(b * 288 + 192 + (d - 96)) * HW);
        U8 t;
        t.s = *(const short8*)(sp + n0 + 8 * g);
        unsigned* dst = (unsigned*)&vs[d * 130 + 8 * g];
        dst[0] = t.u[0]; dst[1] = t.u[1]; dst[2] = t.u[2]; dst[3] = t.u[3];
    }
    __syncthreads();
    int wave = tid >> 6, lane = tid & 63, lr = lane & 15, lg = lane >> 4;
    short8 bf[2][6];
    #pragma unroll
    for (int nt = 0; nt < 2; ++nt) {
        int n = wave * 32 + nt * 16 + lr;
        #pragma unroll
        for (int kk = 0; kk < 6; ++kk) {
            int kb = kk * 32 + lg * 8;
            U8 t;
            #pragma unroll
            for (int j = 0; j < 4; ++j) {
                unsigned e0 = vs[(kb + 2 * j) * 130 + n];
                unsigned e1 = vs[(kb + 2 * j + 1) * 130 + n];
                t.u[j] = e0 | (e1 << 16);
            }
            bf[nt][kk] = t.s;
        }
    }
    float* outb = out + (size_t)b * 96 * HW + n0;
    for (int mt = 0; mt < 6; ++mt) {
        f32x4 acc0 = {0.f, 0.f, 0.f, 0.f}, acc1 = {0.f, 0.f, 0.f, 0.f};
        #pragma unroll
        for (int kk = 0; kk < 6; ++kk) {
            short8 a = *(const short8*)&Mcat[(size_t)(b * 96 + mt * 16 + lr) * 192 + kk * 32 + lg * 8];
            acc0 = mfma16(a, bf[0][kk], acc0);
            acc1 = mfma16(a, bf[1][kk], acc1);
        }
        float* ob_ = obuf[mt & 1];
        #pragma unroll
        for (int r = 0; r < 4; ++r) {
            ob_[(lg * 4 + r) * 132 + wave * 32 + lr]      = acc0[r];
            ob_[(lg * 4 + r) * 132 + wave * 32 + 16 + lr] = acc1[r];
        }
        __syncthreads();
        #pragma unroll
        for (int p = 0; p < 2; ++p) {
            int flat = tid + p * 256;
            int row = flat >> 5, q = flat & 31;
            float4 v = *(const float4*)&ob_[row * 132 + 4 * q];
            float bb = bias[mt * 16 + row];
            v.x += bb; v.y += bb; v.z += bb; v.w += bb;
            *(float4*)&outb[(size_t)(mt * 16 + row) * HW + 4 * q] = v;
        }
    }
}

extern "C" void kernel_launch(void* const* d_in, const int* in_sizes, int n_in,
                              void* d_out, int out_size, void* d_ws, size_t ws_size,
                              hipStream_t stream) {
    const float* low    = (const float*)d_in[0];
    const float* high   = (const float*)d_in[1];
    const float* temp   = (const float*)d_in[2];
    const float* qc_w   = (const float*)d_in[3];
    const float* qdw_c  = (const float*)d_in[4];
    const float* kvc_w  = (const float*)d_in[5];
    const float* kvdw_c = (const float*)d_in[6];
    const float* qt_w   = (const float*)d_in[7];
    const float* qdw_t  = (const float*)d_in[8];
    const float* kvt_w  = (const float*)d_in[9];
    const float* kvdw_t = (const float*)d_in[10];
    const float* po_c   = (const float*)d_in[11];
    const float* po_t   = (const float*)d_in[12];
    const float* cw     = (const float*)d_in[13];
    const float* cb     = (const float*)d_in[14];
    float* out = (float*)d_out;

    char* ws = (char*)d_ws;
    const size_t SY = (size_t)2 * 288 * HW * 2;   // 75,497,472 B per big tensor
    ushort* Y    = (ushort*)(ws);
    ushort* QKVc = (ushort*)(ws + SY);
    ushort* QKVt = (ushort*)(ws + 2 * SY);
    char* p = ws + 3 * SY;
    ushort* Wc = (ushort*)p; p += 288 * 96 * 2;
    ushort* Wt = (ushort*)p; p += 288 * 96 * 2;
    float* W1  = (float*)p;  p += 96 * 96 * 4;
    float* W2  = (float*)p;  p += 96 * 96 * 4;
    float* G   = (float*)p;  p += 12 * 1024 * 4;
    float* SSQ = (float*)p;  p += 8 * 96 * 4;
    ushort* Mcat = (ushort*)p; p += 2 * 96 * 192 * 2;
    if ((size_t)(p - ws) > ws_size) return;

    hipMemsetAsync(G, 0, 12 * 1024 * 4 + 8 * 96 * 4, stream);
    prep_kernel<<<73, 256, 0, stream>>>(qc_w, kvc_w, qt_w, kvt_w, cw, po_c, po_t, Wc, Wt, W1, W2);
    // stream c from high
    conv_kernel<<<dim3(512, 2), 256, 0, stream>>>(high, Wc, Y);
    dw_kernel<<<dim3(8, 576), 256, 0, stream>>>(Y, qdw_c, kvdw_c, QKVc);
    // stream t from low
    conv_kernel<<<dim3(512, 2), 256, 0, stream>>>(low, Wt, Y);
    dw_kernel<<<dim3(8, 576), 256, 0, stream>>>(Y, qdw_t, kvdw_t, QKVt);
    gram_kernel<<<dim3(64, 12), 256, 0, stream>>>(QKVc, QKVt, G, SSQ);
    attn_kernel<<<12, 256, 0, stream>>>(G, SSQ, temp, W1, W2, Mcat);
    final_kernel<<<dim3(512, 2), 256, 0, stream>>>(QKVc, QKVt, Mcat, cb, out);
}